// Round 6
// baseline (720.519 us; speedup 1.0000x reference)
//
#include <hip/hip_runtime.h>

// GCNPre: N=100000 nodes, E=3200000 edges, F=512, H=256, C=40.
#define NN 100000
#define NE 3200000
#define NF 512
#define NH 256
#define NC 40

// CSR-build partitioning: single node chunk (128KB LDS, packed u8 counters).
#define CH 131072                    // >= NN, one chunk
#define NPAD CH
#define PARTS 64
#define SLICE ((NE + PARTS - 1) / PARTS)   // 50000
#define NBLK ((NN + 255) / 256)      // 391

typedef __attribute__((ext_vector_type(8))) short bf16x8;
typedef __attribute__((ext_vector_type(4))) float f32x4;
typedef __attribute__((ext_vector_type(4))) unsigned short u16x4;
typedef __attribute__((ext_vector_type(8))) unsigned short u16x8;

__device__ inline unsigned short f2bf(float f) {
    union { float f; unsigned u; } v; v.f = f;
    unsigned r = v.u + 0x7fffu + ((v.u >> 16) & 1u);
    return (unsigned short)(r >> 16);
}
__device__ inline float bf2f(unsigned short s) {
    union { unsigned u; float f; } v; v.u = ((unsigned)s) << 16;
    return v.f;
}

// ---------------- CSR build (no global atomics, packed u8 LDS counters) ----------------
// Per-(node, slice) counts are Poisson(lambda=0.5): P(>=256) ~ 0, so u8 packing is safe.

// blockIdx = (part, which). Histogram of src[] over the whole node range.
__global__ __launch_bounds__(512) void hist2_kernel(const int* __restrict__ ei,
                                                    unsigned short* __restrict__ rpart16,
                                                    unsigned short* __restrict__ cpart16) {
    __shared__ unsigned h[CH / 4];   // 128KB, u8-packed counters
    const int part = blockIdx.x, which = blockIdx.y;
    const int* src = which ? (ei + NE) : ei;
    unsigned short* outp = which ? cpart16 : rpart16;
    for (int i = threadIdx.x; i < CH / 4; i += 512) h[i] = 0;
    __syncthreads();
    const int e1 = min((part + 1) * SLICE, NE);
    for (int e = part * SLICE + threadIdx.x; e < e1; e += 512) {
        unsigned v = (unsigned)src[e];
        atomicAdd(&h[v >> 2], 1u << ((v & 3) << 3));
    }
    __syncthreads();
    unsigned short* dst = outp + (size_t)part * NPAD;
    for (int i = threadIdx.x; i < CH / 4; i += 512) {
        unsigned v = h[i];
        u16x4 o;
        o[0] = (unsigned short)(v & 0xffu);
        o[1] = (unsigned short)((v >> 8) & 0xffu);
        o[2] = (unsigned short)((v >> 16) & 0xffu);
        o[3] = (unsigned short)(v >> 24);
        *(u16x4*)(dst + i * 4) = o;
    }
}

// Sum partials -> row_cnt, dis; also block sum of row_cnt -> bsum[block].
__global__ __launch_bounds__(256) void reduce_kernel(const unsigned short* __restrict__ rpart16,
                                                     const unsigned short* __restrict__ cpart16,
                                                     int* __restrict__ row_cnt, float* __restrict__ dis,
                                                     int* __restrict__ bsum) {
    __shared__ int s[256];
    const int tid = threadIdx.x;
    const int v = blockIdx.x * 256 + tid;
    unsigned rs = 0, cs = 0;
    if (v < NN) {
        #pragma unroll 1
        for (int p = 0; p < PARTS; p++) {
            rs += rpart16[(size_t)p * NPAD + v];
            cs += cpart16[(size_t)p * NPAD + v];
        }
        row_cnt[v] = (int)rs;
        dis[v] = rsqrtf((float)cs + 1.0f);
    }
    s[tid] = (int)rs;
    __syncthreads();
    #pragma unroll
    for (int o = 128; o > 0; o >>= 1) {
        if (tid < o) s[tid] += s[tid + o];
        __syncthreads();
    }
    if (tid == 0) bsum[blockIdx.x] = s[0];
}

// Exclusive scan of NBLK block sums (single small block).
__global__ __launch_bounds__(512) void scanb_kernel(const int* __restrict__ bsum,
                                                    int* __restrict__ boff) {
    __shared__ int s[512];
    const int t = threadIdx.x;
    int v = (t < NBLK) ? bsum[t] : 0;
    s[t] = v;
    __syncthreads();
    #pragma unroll
    for (int o = 1; o < 512; o <<= 1) {
        int u = (t >= o) ? s[t - o] : 0;
        __syncthreads();
        s[t] += u;
        __syncthreads();
    }
    if (t < NBLK) boff[t] = s[t] - v;   // exclusive
}

// row_ptr[v] = boff[blk] + intra-block exclusive scan; rbase[p][v] = prefix over slices.
__global__ __launch_bounds__(256) void rstart2_kernel(const unsigned short* __restrict__ rpart16,
                                                      const int* __restrict__ row_cnt,
                                                      const int* __restrict__ boff,
                                                      int* __restrict__ row_ptr,
                                                      unsigned* __restrict__ rbase) {
    __shared__ int s[256];
    const int tid = threadIdx.x;
    const int v = blockIdx.x * 256 + tid;
    int cnt = (v < NN) ? row_cnt[v] : 0;
    s[tid] = cnt;
    __syncthreads();
    #pragma unroll
    for (int o = 1; o < 256; o <<= 1) {
        int u = (tid >= o) ? s[tid - o] : 0;
        __syncthreads();
        s[tid] += u;
        __syncthreads();
    }
    if (v < NN) {
        unsigned run = (unsigned)(boff[blockIdx.x] + s[tid] - cnt);
        row_ptr[v] = (int)run;
        #pragma unroll 1
        for (int p = 0; p < PARTS; p++) {
            size_t i = (size_t)p * NPAD + v;
            rbase[i] = run;
            run += rpart16[i];
        }
    }
    if (v == NN) row_ptr[NN] = NE;
}

// Fill packed CSR records {col, w} with packed-u8 LDS cursors; each edge touched once.
__global__ __launch_bounds__(512) void fill2d_kernel(const int* __restrict__ ei,
                                                     const unsigned* __restrict__ rbase,
                                                     const float* __restrict__ dis,
                                                     int2* __restrict__ csr) {
    __shared__ unsigned cur[CH / 4];   // 128KB, u8-packed cursors
    const int part = blockIdx.x;
    for (int i = threadIdx.x; i < CH / 4; i += 512) cur[i] = 0;
    __syncthreads();
    const unsigned* base = rbase + (size_t)part * NPAD;
    const int e1 = min((part + 1) * SLICE, NE);
    for (int e = part * SLICE + threadIdx.x; e < e1; e += 512) {
        int r = ei[e];
        int c = ei[NE + e];
        unsigned sh = ((unsigned)r & 3) << 3;
        unsigned old = atomicAdd(&cur[(unsigned)r >> 2], 1u << sh);
        unsigned p = (old >> sh) & 0xffu;
        unsigned idx = base[r] + p;
        int2 rec;
        rec.x = c;
        rec.y = __float_as_int(dis[r] * dis[c]);
        csr[idx] = rec;
    }
}

// ---------------- weight transpose + bf16 cast (fused) ----------------
__global__ void wtrans_all(const float* __restrict__ Wm, const float* __restrict__ W1,
                           const float* __restrict__ W2, unsigned short* __restrict__ WTm,
                           unsigned short* __restrict__ W1T, unsigned short* __restrict__ W2T) {
    int t = blockIdx.x * 256 + threadIdx.x;
    if (t < NH * NF) {                   // WTm[n][k] = Wm[k][n]
        int n = t / NF, k = t % NF;
        WTm[t] = f2bf(Wm[(long)k * NH + n]);
        return;
    }
    t -= NH * NF;
    if (t < NH * NH) {                   // W1T[n][k] = W1[k][n]
        int n = t / NH, k = t % NH;
        W1T[t] = f2bf(W1[(long)k * NH + n]);
        return;
    }
    t -= NH * NH;
    if (t < 64 * NH) {                   // W2T[n][k] = W2[k][n], padded to 64 rows
        int n = t / NH, k = t % NH;
        W2T[t] = (n < NC) ? f2bf(W2[(long)k * NC + n]) : (unsigned short)0;
    }
}

// ---------------- bf16 MFMA GEMM ----------------
template <int BN, bool A_F32, bool BIAS, bool RELU>
__global__ __launch_bounds__(BN == 256 ? 512 : 256)
void gemm_mfma(const void* __restrict__ Ap, const unsigned short* __restrict__ WT,
               const float* __restrict__ bias, unsigned short* __restrict__ C,
               int M, int K) {
    constexpr int BM = 128, BK = 32;
    constexpr int T = (BN == 256) ? 512 : 256;
    constexpr int WN = (BN == 256) ? 2 : 1;
    constexpr int NREP = BN / (WN * 16);
    constexpr int MREP = 2;
    constexpr int ACH = (BM * BK) / 8;
    constexpr int BCH = (BN * BK) / 8;

    __shared__ short As[BM * BK];
    __shared__ short Bs[BN * BK];

    const int tid = threadIdx.x;
    const int lane = tid & 63;
    const int wid = tid >> 6;
    const int wr = wid / WN;
    const int wc = wid % WN;
    const long bm = (long)blockIdx.x * BM;

    f32x4 acc[MREP][NREP];
    #pragma unroll
    for (int i = 0; i < MREP; i++)
        #pragma unroll
        for (int j = 0; j < NREP; j++)
            acc[i][j] = (f32x4){0.f, 0.f, 0.f, 0.f};

    const float* Af = (const float*)Ap;
    const unsigned short* Ab = (const unsigned short*)Ap;

    for (int k0 = 0; k0 < K; k0 += BK) {
        #pragma unroll
        for (int i = 0; i < ACH / T; i++) {
            int ch = tid + i * T;
            int row = ch >> 2, c = ch & 3;
            int sw = c ^ (row & 3) ^ ((row >> 2) & 3);
            long gr = bm + row;
            bf16x8 w;
            if (gr < M) {
                if (A_F32) {
                    float4 v0 = *(const float4*)(Af + gr * K + k0 + c * 8);
                    float4 v1 = *(const float4*)(Af + gr * K + k0 + c * 8 + 4);
                    w[0] = (short)f2bf(v0.x); w[1] = (short)f2bf(v0.y);
                    w[2] = (short)f2bf(v0.z); w[3] = (short)f2bf(v0.w);
                    w[4] = (short)f2bf(v1.x); w[5] = (short)f2bf(v1.y);
                    w[6] = (short)f2bf(v1.z); w[7] = (short)f2bf(v1.w);
                } else {
                    w = *(const bf16x8*)(Ab + gr * K + k0 + c * 8);
                }
            } else {
                w = (bf16x8){0, 0, 0, 0, 0, 0, 0, 0};
            }
            *(bf16x8*)(As + row * BK + sw * 8) = w;
        }
        #pragma unroll
        for (int i = 0; i < BCH / T; i++) {
            int ch = tid + i * T;
            int row = ch >> 2, c = ch & 3;
            int sw = c ^ (row & 3) ^ ((row >> 2) & 3);
            bf16x8 w = *(const bf16x8*)(WT + (long)row * K + k0 + c * 8);
            *(bf16x8*)(Bs + row * BK + sw * 8) = w;
        }
        __syncthreads();

        const int l15 = lane & 15, g = lane >> 4;
        bf16x8 a[MREP];
        #pragma unroll
        for (int mi = 0; mi < MREP; mi++) {
            int row = wr * 32 + mi * 16 + l15;
            int sw = g ^ (row & 3) ^ ((row >> 2) & 3);
            a[mi] = *(const bf16x8*)(As + row * BK + sw * 8);
        }
        #pragma unroll
        for (int ni = 0; ni < NREP; ni++) {
            int row = wc * (NREP * 16) + ni * 16 + l15;
            int sw = g ^ (row & 3) ^ ((row >> 2) & 3);
            bf16x8 b = *(const bf16x8*)(Bs + row * BK + sw * 8);
            #pragma unroll
            for (int mi = 0; mi < MREP; mi++)
                acc[mi][ni] = __builtin_amdgcn_mfma_f32_16x16x32_bf16(a[mi], b, acc[mi][ni], 0, 0, 0);
        }
        __syncthreads();
    }

    const int l15 = lane & 15, l4 = lane >> 4;
    #pragma unroll
    for (int mi = 0; mi < MREP; mi++) {
        long gr0 = bm + wr * 32 + mi * 16 + l4 * 4;
        #pragma unroll
        for (int ni = 0; ni < NREP; ni++) {
            int gc = wc * (NREP * 16) + ni * 16 + l15;
            float bv = BIAS ? bias[gc] : 0.f;
            #pragma unroll
            for (int q = 0; q < 4; q++) {
                long gr = gr0 + q;
                if (gr < M) {
                    float v = acc[mi][ni][q] + bv;
                    if (RELU) v = fmaxf(v, 0.f);
                    C[gr * BN + gc] = f2bf(v);
                }
            }
        }
    }
}

// ---------------- aggregation (gather SpMM, bf16 payload) ----------------
// agg256: wave = 1 node; two 32-lane halves own alternate edges; lane gathers
// u16x8 (16B) so one instruction fetches two full 512B rows. 4-deep unroll.
__global__ void agg256_kernel(const unsigned short* __restrict__ t, const int* __restrict__ row_ptr,
                              const int2* __restrict__ csr, const float* __restrict__ dis,
                              const float* __restrict__ bias, unsigned short* __restrict__ out, int n) {
    const int wid = threadIdx.x >> 6, lane = threadIdx.x & 63;
    const int node = blockIdx.x * 4 + wid;
    if (node >= n) return;
    const int half = lane >> 5;
    const int f0 = (lane & 31) * 8;
    const float d = dis[node];
    float a[8];
    if (half == 0) {
        u16x8 sv = *(const u16x8*)(t + (long)node * NH + f0);
        float d2 = d * d;
        #pragma unroll
        for (int j = 0; j < 8; j++) a[j] = bf2f(sv[j]) * d2;
    } else {
        #pragma unroll
        for (int j = 0; j < 8; j++) a[j] = 0.f;
    }
    const int lo = row_ptr[node], hi = row_ptr[node + 1];
    int ee = lo + half;
    for (; ee + 6 < hi; ee += 8) {
        int2 r0 = csr[ee];
        int2 r1 = csr[ee + 2];
        int2 r2 = csr[ee + 4];
        int2 r3 = csr[ee + 6];
        u16x8 v0 = *(const u16x8*)(t + (long)r0.x * NH + f0);
        u16x8 v1 = *(const u16x8*)(t + (long)r1.x * NH + f0);
        u16x8 v2 = *(const u16x8*)(t + (long)r2.x * NH + f0);
        u16x8 v3 = *(const u16x8*)(t + (long)r3.x * NH + f0);
        float w0 = __int_as_float(r0.y), w1 = __int_as_float(r1.y);
        float w2 = __int_as_float(r2.y), w3 = __int_as_float(r3.y);
        #pragma unroll
        for (int j = 0; j < 8; j++)
            a[j] += (bf2f(v0[j]) * w0 + bf2f(v1[j]) * w1) + (bf2f(v2[j]) * w2 + bf2f(v3[j]) * w3);
    }
    for (; ee + 2 < hi; ee += 4) {
        int2 r0 = csr[ee];
        int2 r1 = csr[ee + 2];
        u16x8 v0 = *(const u16x8*)(t + (long)r0.x * NH + f0);
        u16x8 v1 = *(const u16x8*)(t + (long)r1.x * NH + f0);
        float w0 = __int_as_float(r0.y), w1 = __int_as_float(r1.y);
        #pragma unroll
        for (int j = 0; j < 8; j++)
            a[j] += bf2f(v0[j]) * w0 + bf2f(v1[j]) * w1;
    }
    if (ee < hi) {
        int2 r0 = csr[ee];
        u16x8 v0 = *(const u16x8*)(t + (long)r0.x * NH + f0);
        float w0 = __int_as_float(r0.y);
        #pragma unroll
        for (int j = 0; j < 8; j++) a[j] += bf2f(v0[j]) * w0;
    }
    #pragma unroll
    for (int j = 0; j < 8; j++) a[j] += __shfl_xor(a[j], 32);
    if (half == 0) {
        u16x8 o;
        #pragma unroll
        for (int j = 0; j < 8; j++)
            o[j] = f2bf(fmaxf(a[j] + bias[f0 + j], 0.f));
        *(u16x8*)(out + (long)node * NH + f0) = o;
    }
}

// agg40: wave = 1 node; 8 groups of 8 lanes; each group owns every-8th edge;
// only lanes with f0 < 40 gather (80B useful per 128B row).
__global__ void agg40_kernel(const unsigned short* __restrict__ t, const int* __restrict__ row_ptr,
                             const int2* __restrict__ csr, const float* __restrict__ dis,
                             const float* __restrict__ bias, float* __restrict__ out, int n) {
    const int wid = threadIdx.x >> 6, lane = threadIdx.x & 63;
    const int node = blockIdx.x * 4 + wid;
    if (node >= n) return;
    const int g = lane >> 3;
    const int f0 = (lane & 7) * 8;
    const bool act = f0 < NC;       // lanes 0..4 of each 8-lane group
    const float d = dis[node];
    float a[8];
    #pragma unroll
    for (int j = 0; j < 8; j++) a[j] = 0.f;
    const int lo = row_ptr[node], hi = row_ptr[node + 1];
    if (act) {
        if (g == 0) {
            u16x8 sv = *(const u16x8*)(t + (long)node * 64 + f0);
            float d2 = d * d;
            #pragma unroll
            for (int j = 0; j < 8; j++) a[j] = bf2f(sv[j]) * d2;
        }
        int ee = lo + g;
        for (; ee + 8 < hi; ee += 16) {
            int2 r0 = csr[ee];
            int2 r1 = csr[ee + 8];
            u16x8 v0 = *(const u16x8*)(t + (long)r0.x * 64 + f0);
            u16x8 v1 = *(const u16x8*)(t + (long)r1.x * 64 + f0);
            float w0 = __int_as_float(r0.y), w1 = __int_as_float(r1.y);
            #pragma unroll
            for (int j = 0; j < 8; j++)
                a[j] += bf2f(v0[j]) * w0 + bf2f(v1[j]) * w1;
        }
        if (ee < hi) {
            int2 r0 = csr[ee];
            u16x8 v0 = *(const u16x8*)(t + (long)r0.x * 64 + f0);
            float w0 = __int_as_float(r0.y);
            #pragma unroll
            for (int j = 0; j < 8; j++) a[j] += bf2f(v0[j]) * w0;
        }
    }
    #pragma unroll
    for (int s = 8; s < 64; s <<= 1)
        #pragma unroll
        for (int j = 0; j < 8; j++) a[j] += __shfl_xor(a[j], s);
    if (g == 0 && act) {
        float4 o0, o1;
        o0.x = a[0] + bias[f0 + 0]; o0.y = a[1] + bias[f0 + 1];
        o0.z = a[2] + bias[f0 + 2]; o0.w = a[3] + bias[f0 + 3];
        o1.x = a[4] + bias[f0 + 4]; o1.y = a[5] + bias[f0 + 5];
        o1.z = a[6] + bias[f0 + 6]; o1.w = a[7] + bias[f0 + 7];
        float* dst = out + (long)node * NC + f0;
        *(float4*)dst = o0;
        *(float4*)(dst + 4) = o1;
    }
}

// ---------------- launch ----------------

extern "C" void kernel_launch(void* const* d_in, const int* in_sizes, int n_in,
                              void* d_out, int out_size, void* d_ws, size_t ws_size,
                              hipStream_t stream) {
    const float* x     = (const float*)d_in[0];
    const int*   ei    = (const int*)d_in[1];
    const float* W_mlp = (const float*)d_in[2];
    const float* b_mlp = (const float*)d_in[3];
    const float* W1    = (const float*)d_in[4];
    const float* b1    = (const float*)d_in[5];
    const float* W2    = (const float*)d_in[6];
    const float* b2    = (const float*)d_in[7];
    float* out = (float*)d_out;

    // workspace layout (float units)
    float* ws = (float*)d_ws;
    size_t off = 0;
    float*    dis     = ws + off; off += 100096;
    int*      row_cnt = (int*)(ws + off); off += 100096;
    int*      row_ptr = (int*)(ws + off); off += 100096;
    int*      bsum    = (int*)(ws + off); off += 512;
    int*      boff    = (int*)(ws + off); off += 512;
    unsigned short* rpart16 = (unsigned short*)(ws + off); off += (size_t)PARTS * NPAD / 2;
    unsigned short* cpart16 = (unsigned short*)(ws + off); off += (size_t)PARTS * NPAD / 2;
    unsigned* rbase   = (unsigned*)(ws + off); off += (size_t)PARTS * NPAD;
    int2*     csr     = (int2*)(ws + off); off += (size_t)NE * 2;
    unsigned short* WTm = (unsigned short*)(ws + off); off += (NH * NF) / 2;
    unsigned short* W1T = (unsigned short*)(ws + off); off += (NH * NH) / 2;
    unsigned short* W2T = (unsigned short*)(ws + off); off += (64 * NH) / 2;
    unsigned short* h0  = (unsigned short*)(ws + off); off += (size_t)NN * NH / 2;
    unsigned short* t1  = (unsigned short*)(ws + off); off += (size_t)NN * NH / 2;
    unsigned short* t2p = (unsigned short*)(ws + off); off += (size_t)NN * 64 / 2;
    unsigned short* h1  = h0;   // h0 dead after gemm2; alias to save 51MB
    (void)ws_size;

    dim3 gh(PARTS, 2);
    hist2_kernel<<<gh, 512, 0, stream>>>(ei, rpart16, cpart16);
    reduce_kernel<<<NBLK, 256, 0, stream>>>(rpart16, cpart16, row_cnt, dis, bsum);
    scanb_kernel<<<1, 512, 0, stream>>>(bsum, boff);
    rstart2_kernel<<<NBLK, 256, 0, stream>>>(rpart16, row_cnt, boff, row_ptr, rbase);
    fill2d_kernel<<<PARTS, 512, 0, stream>>>(ei, rbase, dis, csr);

    wtrans_all<<<(NH * NF + NH * NH + 64 * NH + 255) / 256, 256, 0, stream>>>(
        W_mlp, W1, W2, WTm, W1T, W2T);

    const int mb = (NN + 127) / 128;  // 782
    gemm_mfma<256, true, true, true><<<mb, 512, 0, stream>>>(x, WTm, b_mlp, h0, NN, NF);
    gemm_mfma<256, false, false, false><<<mb, 512, 0, stream>>>(h0, W1T, nullptr, t1, NN, NH);
    agg256_kernel<<<(NN + 3) / 4, 256, 0, stream>>>(t1, row_ptr, csr, dis, b1, h1, NN);
    gemm_mfma<64, false, false, false><<<mb, 256, 0, stream>>>(h1, W2T, nullptr, t2p, NN, NH);
    agg40_kernel<<<(NN + 3) / 4, 256, 0, stream>>>(t2p, row_ptr, csr, dis, b2, out, NN);
}

// Round 7
// 595.233 us; speedup vs baseline: 1.2105x; 1.2105x over previous
//
#include <hip/hip_runtime.h>

// GCNPre: N=100000 nodes, E=3200000 edges, F=512, H=256, C=40.
#define NN 100000
#define NE 3200000
#define NF 512
#define NH 256
#define NC 40

// CSR-build partitioning: node chunks of 32768 (64KB LDS, packed u16x2 counters).
// 256 blocks per pass keeps all CUs busy (round-6 lesson: single-chunk = 64 blocks = disaster).
#define CH 32768
#define NCH 4                        // 4*32768 = 131072 >= NN
#define NPAD (NCH * CH)              // 131072
#define PARTS 64
#define SLICE ((NE + PARTS - 1) / PARTS)   // 50000
#define NBLK ((NN + 255) / 256)      // 391

typedef __attribute__((ext_vector_type(8))) short bf16x8;
typedef __attribute__((ext_vector_type(4))) float f32x4;
typedef __attribute__((ext_vector_type(4))) unsigned short u16x4;
typedef __attribute__((ext_vector_type(8))) unsigned short u16x8;

__device__ inline unsigned short f2bf(float f) {
    union { float f; unsigned u; } v; v.f = f;
    unsigned r = v.u + 0x7fffu + ((v.u >> 16) & 1u);
    return (unsigned short)(r >> 16);
}
__device__ inline float bf2f(unsigned short s) {
    union { unsigned u; float f; } v; v.u = ((unsigned)s) << 16;
    return v.f;
}

// ---------------- CSR build (no global atomics) ----------------
// Per-(chunk,slice,node) counts are Poisson(0.5): max ~10 << 255, so u8 partials are safe.

// blockIdx = (chunk, part, which). Histogram src[] values in [chunk*CH, chunk*CH+CH).
__global__ __launch_bounds__(512) void hist2_kernel(const int* __restrict__ ei,
                                                    unsigned char* __restrict__ rpart8,
                                                    unsigned char* __restrict__ cpart8) {
    __shared__ unsigned h[CH / 2];   // u16-packed counters, 64KB
    const int chunk = blockIdx.x, part = blockIdx.y, which = blockIdx.z;
    const int* src = which ? (ei + NE) : ei;
    unsigned char* outp = which ? cpart8 : rpart8;
    const int lo = chunk * CH;
    for (int i = threadIdx.x; i < CH / 2; i += 512) h[i] = 0;
    __syncthreads();
    const int e1 = min((part + 1) * SLICE, NE);
    for (int e = part * SLICE + threadIdx.x; e < e1; e += 512) {
        unsigned v = (unsigned)(src[e] - lo);
        if (v < CH) atomicAdd(&h[v >> 1], 1u << ((v & 1) << 4));
    }
    __syncthreads();
    unsigned char* dst = outp + (size_t)part * NPAD + lo;
    for (int i = threadIdx.x; i < CH; i += 512)
        dst[i] = (unsigned char)((h[i >> 1] >> ((i & 1) << 4)) & 0xffu);
}

// Sum partials -> row_cnt, dis; also block sum of row_cnt -> bsum[block].
__global__ __launch_bounds__(256) void reduce_kernel(const unsigned char* __restrict__ rpart8,
                                                     const unsigned char* __restrict__ cpart8,
                                                     int* __restrict__ row_cnt, float* __restrict__ dis,
                                                     int* __restrict__ bsum) {
    __shared__ int s[256];
    const int tid = threadIdx.x;
    const int v = blockIdx.x * 256 + tid;
    unsigned rs = 0, cs = 0;
    if (v < NN) {
        #pragma unroll 1
        for (int p = 0; p < PARTS; p++) {
            rs += rpart8[(size_t)p * NPAD + v];
            cs += cpart8[(size_t)p * NPAD + v];
        }
        row_cnt[v] = (int)rs;
        dis[v] = rsqrtf((float)cs + 1.0f);
    }
    s[tid] = (int)rs;
    __syncthreads();
    #pragma unroll
    for (int o = 128; o > 0; o >>= 1) {
        if (tid < o) s[tid] += s[tid + o];
        __syncthreads();
    }
    if (tid == 0) bsum[blockIdx.x] = s[0];
}

// Exclusive scan of NBLK block sums (single small block).
__global__ __launch_bounds__(512) void scanb_kernel(const int* __restrict__ bsum,
                                                    int* __restrict__ boff) {
    __shared__ int s[512];
    const int t = threadIdx.x;
    int v = (t < NBLK) ? bsum[t] : 0;
    s[t] = v;
    __syncthreads();
    #pragma unroll
    for (int o = 1; o < 512; o <<= 1) {
        int u = (t >= o) ? s[t - o] : 0;
        __syncthreads();
        s[t] += u;
        __syncthreads();
    }
    if (t < NBLK) boff[t] = s[t] - v;   // exclusive
}

// row_ptr[v] = boff[blk] + intra-block exclusive scan; rbase[p][v] = prefix over slices.
__global__ __launch_bounds__(256) void rstart2_kernel(const unsigned char* __restrict__ rpart8,
                                                      const int* __restrict__ row_cnt,
                                                      const int* __restrict__ boff,
                                                      int* __restrict__ row_ptr,
                                                      unsigned* __restrict__ rbase) {
    __shared__ int s[256];
    const int tid = threadIdx.x;
    const int v = blockIdx.x * 256 + tid;
    int cnt = (v < NN) ? row_cnt[v] : 0;
    s[tid] = cnt;
    __syncthreads();
    #pragma unroll
    for (int o = 1; o < 256; o <<= 1) {
        int u = (tid >= o) ? s[tid - o] : 0;
        __syncthreads();
        s[tid] += u;
        __syncthreads();
    }
    if (v < NN) {
        unsigned run = (unsigned)(boff[blockIdx.x] + s[tid] - cnt);
        row_ptr[v] = (int)run;
        #pragma unroll 1
        for (int p = 0; p < PARTS; p++) {
            size_t i = (size_t)p * NPAD + v;
            rbase[i] = run;
            run += rpart8[i];
        }
    }
    if (v == NN) row_ptr[NN] = NE;
}

// Fill packed CSR records {col, w} with packed-u16 LDS cursors (no global atomics).
__global__ __launch_bounds__(512) void fill2d_kernel(const int* __restrict__ ei,
                                                     const unsigned* __restrict__ rbase,
                                                     const float* __restrict__ dis,
                                                     int2* __restrict__ csr) {
    __shared__ unsigned cur[CH / 2];
    const int chunk = blockIdx.x, part = blockIdx.y;
    const int lo = chunk * CH;
    for (int i = threadIdx.x; i < CH / 2; i += 512) cur[i] = 0;
    __syncthreads();
    const unsigned* base = rbase + (size_t)part * NPAD + lo;
    const int e1 = min((part + 1) * SLICE, NE);
    for (int e = part * SLICE + threadIdx.x; e < e1; e += 512) {
        int r = ei[e];
        unsigned rr = (unsigned)(r - lo);
        if (rr < CH) {
            int c = ei[NE + e];
            unsigned sh = (rr & 1) << 4;
            unsigned old = atomicAdd(&cur[rr >> 1], 1u << sh);
            unsigned p = (old >> sh) & 0xffffu;
            unsigned idx = base[rr] + p;
            int2 rec;
            rec.x = c;
            rec.y = __float_as_int(dis[r] * dis[c]);
            csr[idx] = rec;
        }
    }
}

// ---------------- weight transpose + bf16 cast (fused) ----------------
__global__ void wtrans_all(const float* __restrict__ Wm, const float* __restrict__ W1,
                           const float* __restrict__ W2, unsigned short* __restrict__ WTm,
                           unsigned short* __restrict__ W1T, unsigned short* __restrict__ W2T) {
    int t = blockIdx.x * 256 + threadIdx.x;
    if (t < NH * NF) {                   // WTm[n][k] = Wm[k][n]
        int n = t / NF, k = t % NF;
        WTm[t] = f2bf(Wm[(long)k * NH + n]);
        return;
    }
    t -= NH * NF;
    if (t < NH * NH) {                   // W1T[n][k] = W1[k][n]
        int n = t / NH, k = t % NH;
        W1T[t] = f2bf(W1[(long)k * NH + n]);
        return;
    }
    t -= NH * NH;
    if (t < 64 * NH) {                   // W2T[n][k] = W2[k][n], padded to 64 rows
        int n = t / NH, k = t % NH;
        W2T[t] = (n < NC) ? f2bf(W2[(long)k * NC + n]) : (unsigned short)0;
    }
}

// ---------------- bf16 MFMA GEMM ----------------
template <int BN, bool A_F32, bool BIAS, bool RELU>
__global__ __launch_bounds__(BN == 256 ? 512 : 256)
void gemm_mfma(const void* __restrict__ Ap, const unsigned short* __restrict__ WT,
               const float* __restrict__ bias, unsigned short* __restrict__ C,
               int M, int K) {
    constexpr int BM = 128, BK = 32;
    constexpr int T = (BN == 256) ? 512 : 256;
    constexpr int WN = (BN == 256) ? 2 : 1;
    constexpr int NREP = BN / (WN * 16);
    constexpr int MREP = 2;
    constexpr int ACH = (BM * BK) / 8;
    constexpr int BCH = (BN * BK) / 8;

    __shared__ short As[BM * BK];
    __shared__ short Bs[BN * BK];

    const int tid = threadIdx.x;
    const int lane = tid & 63;
    const int wid = tid >> 6;
    const int wr = wid / WN;
    const int wc = wid % WN;
    const long bm = (long)blockIdx.x * BM;

    f32x4 acc[MREP][NREP];
    #pragma unroll
    for (int i = 0; i < MREP; i++)
        #pragma unroll
        for (int j = 0; j < NREP; j++)
            acc[i][j] = (f32x4){0.f, 0.f, 0.f, 0.f};

    const float* Af = (const float*)Ap;
    const unsigned short* Ab = (const unsigned short*)Ap;

    for (int k0 = 0; k0 < K; k0 += BK) {
        #pragma unroll
        for (int i = 0; i < ACH / T; i++) {
            int ch = tid + i * T;
            int row = ch >> 2, c = ch & 3;
            int sw = c ^ (row & 3) ^ ((row >> 2) & 3);
            long gr = bm + row;
            bf16x8 w;
            if (gr < M) {
                if (A_F32) {
                    float4 v0 = *(const float4*)(Af + gr * K + k0 + c * 8);
                    float4 v1 = *(const float4*)(Af + gr * K + k0 + c * 8 + 4);
                    w[0] = (short)f2bf(v0.x); w[1] = (short)f2bf(v0.y);
                    w[2] = (short)f2bf(v0.z); w[3] = (short)f2bf(v0.w);
                    w[4] = (short)f2bf(v1.x); w[5] = (short)f2bf(v1.y);
                    w[6] = (short)f2bf(v1.z); w[7] = (short)f2bf(v1.w);
                } else {
                    w = *(const bf16x8*)(Ab + gr * K + k0 + c * 8);
                }
            } else {
                w = (bf16x8){0, 0, 0, 0, 0, 0, 0, 0};
            }
            *(bf16x8*)(As + row * BK + sw * 8) = w;
        }
        #pragma unroll
        for (int i = 0; i < BCH / T; i++) {
            int ch = tid + i * T;
            int row = ch >> 2, c = ch & 3;
            int sw = c ^ (row & 3) ^ ((row >> 2) & 3);
            bf16x8 w = *(const bf16x8*)(WT + (long)row * K + k0 + c * 8);
            *(bf16x8*)(Bs + row * BK + sw * 8) = w;
        }
        __syncthreads();

        const int l15 = lane & 15, g = lane >> 4;
        bf16x8 a[MREP];
        #pragma unroll
        for (int mi = 0; mi < MREP; mi++) {
            int row = wr * 32 + mi * 16 + l15;
            int sw = g ^ (row & 3) ^ ((row >> 2) & 3);
            a[mi] = *(const bf16x8*)(As + row * BK + sw * 8);
        }
        #pragma unroll
        for (int ni = 0; ni < NREP; ni++) {
            int row = wc * (NREP * 16) + ni * 16 + l15;
            int sw = g ^ (row & 3) ^ ((row >> 2) & 3);
            bf16x8 b = *(const bf16x8*)(Bs + row * BK + sw * 8);
            #pragma unroll
            for (int mi = 0; mi < MREP; mi++)
                acc[mi][ni] = __builtin_amdgcn_mfma_f32_16x16x32_bf16(a[mi], b, acc[mi][ni], 0, 0, 0);
        }
        __syncthreads();
    }

    const int l15 = lane & 15, l4 = lane >> 4;
    #pragma unroll
    for (int mi = 0; mi < MREP; mi++) {
        long gr0 = bm + wr * 32 + mi * 16 + l4 * 4;
        #pragma unroll
        for (int ni = 0; ni < NREP; ni++) {
            int gc = wc * (NREP * 16) + ni * 16 + l15;
            float bv = BIAS ? bias[gc] : 0.f;
            #pragma unroll
            for (int q = 0; q < 4; q++) {
                long gr = gr0 + q;
                if (gr < M) {
                    float v = acc[mi][ni][q] + bv;
                    if (RELU) v = fmaxf(v, 0.f);
                    C[gr * BN + gc] = f2bf(v);
                }
            }
        }
    }
}

// ---------------- aggregation (gather SpMM, bf16 payload) ----------------
// agg256: wave = 1 node; two 32-lane halves own alternate edges; lane gathers
// u16x8 (16B) so one instruction fetches two full 512B rows. 4-deep unroll.
__global__ void agg256_kernel(const unsigned short* __restrict__ t, const int* __restrict__ row_ptr,
                              const int2* __restrict__ csr, const float* __restrict__ dis,
                              const float* __restrict__ bias, unsigned short* __restrict__ out, int n) {
    const int wid = threadIdx.x >> 6, lane = threadIdx.x & 63;
    const int node = blockIdx.x * 4 + wid;
    if (node >= n) return;
    const int half = lane >> 5;
    const int f0 = (lane & 31) * 8;
    const float d = dis[node];
    float a[8];
    if (half == 0) {
        u16x8 sv = *(const u16x8*)(t + (long)node * NH + f0);
        float d2 = d * d;
        #pragma unroll
        for (int j = 0; j < 8; j++) a[j] = bf2f(sv[j]) * d2;
    } else {
        #pragma unroll
        for (int j = 0; j < 8; j++) a[j] = 0.f;
    }
    const int lo = row_ptr[node], hi = row_ptr[node + 1];
    int ee = lo + half;
    for (; ee + 6 < hi; ee += 8) {
        int2 r0 = csr[ee];
        int2 r1 = csr[ee + 2];
        int2 r2 = csr[ee + 4];
        int2 r3 = csr[ee + 6];
        u16x8 v0 = *(const u16x8*)(t + (long)r0.x * NH + f0);
        u16x8 v1 = *(const u16x8*)(t + (long)r1.x * NH + f0);
        u16x8 v2 = *(const u16x8*)(t + (long)r2.x * NH + f0);
        u16x8 v3 = *(const u16x8*)(t + (long)r3.x * NH + f0);
        float w0 = __int_as_float(r0.y), w1 = __int_as_float(r1.y);
        float w2 = __int_as_float(r2.y), w3 = __int_as_float(r3.y);
        #pragma unroll
        for (int j = 0; j < 8; j++)
            a[j] += (bf2f(v0[j]) * w0 + bf2f(v1[j]) * w1) + (bf2f(v2[j]) * w2 + bf2f(v3[j]) * w3);
    }
    for (; ee + 2 < hi; ee += 4) {
        int2 r0 = csr[ee];
        int2 r1 = csr[ee + 2];
        u16x8 v0 = *(const u16x8*)(t + (long)r0.x * NH + f0);
        u16x8 v1 = *(const u16x8*)(t + (long)r1.x * NH + f0);
        float w0 = __int_as_float(r0.y), w1 = __int_as_float(r1.y);
        #pragma unroll
        for (int j = 0; j < 8; j++)
            a[j] += bf2f(v0[j]) * w0 + bf2f(v1[j]) * w1;
    }
    if (ee < hi) {
        int2 r0 = csr[ee];
        u16x8 v0 = *(const u16x8*)(t + (long)r0.x * NH + f0);
        float w0 = __int_as_float(r0.y);
        #pragma unroll
        for (int j = 0; j < 8; j++) a[j] += bf2f(v0[j]) * w0;
    }
    #pragma unroll
    for (int j = 0; j < 8; j++) a[j] += __shfl_xor(a[j], 32);
    if (half == 0) {
        u16x8 o;
        #pragma unroll
        for (int j = 0; j < 8; j++)
            o[j] = f2bf(fmaxf(a[j] + bias[f0 + j], 0.f));
        *(u16x8*)(out + (long)node * NH + f0) = o;
    }
}

// agg40: wave = 1 node; 8 groups of 8 lanes; each group owns every-8th edge;
// only lanes with f0 < 40 gather.
__global__ void agg40_kernel(const unsigned short* __restrict__ t, const int* __restrict__ row_ptr,
                             const int2* __restrict__ csr, const float* __restrict__ dis,
                             const float* __restrict__ bias, float* __restrict__ out, int n) {
    const int wid = threadIdx.x >> 6, lane = threadIdx.x & 63;
    const int node = blockIdx.x * 4 + wid;
    if (node >= n) return;
    const int g = lane >> 3;
    const int f0 = (lane & 7) * 8;
    const bool act = f0 < NC;       // lanes 0..4 of each 8-lane group
    const float d = dis[node];
    float a[8];
    #pragma unroll
    for (int j = 0; j < 8; j++) a[j] = 0.f;
    const int lo = row_ptr[node], hi = row_ptr[node + 1];
    if (act) {
        if (g == 0) {
            u16x8 sv = *(const u16x8*)(t + (long)node * 64 + f0);
            float d2 = d * d;
            #pragma unroll
            for (int j = 0; j < 8; j++) a[j] = bf2f(sv[j]) * d2;
        }
        int ee = lo + g;
        for (; ee + 8 < hi; ee += 16) {
            int2 r0 = csr[ee];
            int2 r1 = csr[ee + 8];
            u16x8 v0 = *(const u16x8*)(t + (long)r0.x * 64 + f0);
            u16x8 v1 = *(const u16x8*)(t + (long)r1.x * 64 + f0);
            float w0 = __int_as_float(r0.y), w1 = __int_as_float(r1.y);
            #pragma unroll
            for (int j = 0; j < 8; j++)
                a[j] += bf2f(v0[j]) * w0 + bf2f(v1[j]) * w1;
        }
        if (ee < hi) {
            int2 r0 = csr[ee];
            u16x8 v0 = *(const u16x8*)(t + (long)r0.x * 64 + f0);
            float w0 = __int_as_float(r0.y);
            #pragma unroll
            for (int j = 0; j < 8; j++) a[j] += bf2f(v0[j]) * w0;
        }
    }
    #pragma unroll
    for (int s = 8; s < 64; s <<= 1)
        #pragma unroll
        for (int j = 0; j < 8; j++) a[j] += __shfl_xor(a[j], s);
    if (g == 0 && act) {
        float4 o0, o1;
        o0.x = a[0] + bias[f0 + 0]; o0.y = a[1] + bias[f0 + 1];
        o0.z = a[2] + bias[f0 + 2]; o0.w = a[3] + bias[f0 + 3];
        o1.x = a[4] + bias[f0 + 4]; o1.y = a[5] + bias[f0 + 5];
        o1.z = a[6] + bias[f0 + 6]; o1.w = a[7] + bias[f0 + 7];
        float* dst = out + (long)node * NC + f0;
        *(float4*)dst = o0;
        *(float4*)(dst + 4) = o1;
    }
}

// ---------------- launch ----------------

extern "C" void kernel_launch(void* const* d_in, const int* in_sizes, int n_in,
                              void* d_out, int out_size, void* d_ws, size_t ws_size,
                              hipStream_t stream) {
    const float* x     = (const float*)d_in[0];
    const int*   ei    = (const int*)d_in[1];
    const float* W_mlp = (const float*)d_in[2];
    const float* b_mlp = (const float*)d_in[3];
    const float* W1    = (const float*)d_in[4];
    const float* b1    = (const float*)d_in[5];
    const float* W2    = (const float*)d_in[6];
    const float* b2    = (const float*)d_in[7];
    float* out = (float*)d_out;

    // workspace layout (float units)
    float* ws = (float*)d_ws;
    size_t off = 0;
    float*    dis     = ws + off; off += 100096;
    int*      row_cnt = (int*)(ws + off); off += 100096;
    int*      row_ptr = (int*)(ws + off); off += 100096;
    int*      bsum    = (int*)(ws + off); off += 512;
    int*      boff    = (int*)(ws + off); off += 512;
    unsigned char* rpart8 = (unsigned char*)(ws + off); off += (size_t)PARTS * NPAD / 4;
    unsigned char* cpart8 = (unsigned char*)(ws + off); off += (size_t)PARTS * NPAD / 4;
    unsigned* rbase   = (unsigned*)(ws + off); off += (size_t)PARTS * NPAD;
    int2*     csr     = (int2*)(ws + off); off += (size_t)NE * 2;
    unsigned short* WTm = (unsigned short*)(ws + off); off += (NH * NF) / 2;
    unsigned short* W1T = (unsigned short*)(ws + off); off += (NH * NH) / 2;
    unsigned short* W2T = (unsigned short*)(ws + off); off += (64 * NH) / 2;
    unsigned short* h0  = (unsigned short*)(ws + off); off += (size_t)NN * NH / 2;
    unsigned short* t1  = (unsigned short*)(ws + off); off += (size_t)NN * NH / 2;
    unsigned short* t2p = (unsigned short*)(ws + off); off += (size_t)NN * 64 / 2;
    unsigned short* h1  = h0;   // h0 dead after gemm2; alias to save 51MB
    (void)ws_size;

    dim3 gh(NCH, PARTS, 2);
    hist2_kernel<<<gh, 512, 0, stream>>>(ei, rpart8, cpart8);
    reduce_kernel<<<NBLK, 256, 0, stream>>>(rpart8, cpart8, row_cnt, dis, bsum);
    scanb_kernel<<<1, 512, 0, stream>>>(bsum, boff);
    rstart2_kernel<<<NBLK, 256, 0, stream>>>(rpart8, row_cnt, boff, row_ptr, rbase);
    dim3 gf(NCH, PARTS);
    fill2d_kernel<<<gf, 512, 0, stream>>>(ei, rbase, dis, csr);

    wtrans_all<<<(NH * NF + NH * NH + 64 * NH + 255) / 256, 256, 0, stream>>>(
        W_mlp, W1, W2, WTm, W1T, W2T);

    const int mb = (NN + 127) / 128;  // 782
    gemm_mfma<256, true, true, true><<<mb, 512, 0, stream>>>(x, WTm, b_mlp, h0, NN, NF);
    gemm_mfma<256, false, false, false><<<mb, 512, 0, stream>>>(h0, W1T, nullptr, t1, NN, NH);
    agg256_kernel<<<(NN + 3) / 4, 256, 0, stream>>>(t1, row_ptr, csr, dis, b1, h1, NN);
    gemm_mfma<64, false, false, false><<<mb, 256, 0, stream>>>(h1, W2T, nullptr, t2p, NN, NH);
    agg40_kernel<<<(NN + 3) / 4, 256, 0, stream>>>(t2p, row_ptr, csr, dis, b2, out, NN);
}

// Round 8
// 582.073 us; speedup vs baseline: 1.2378x; 1.0226x over previous
//
#include <hip/hip_runtime.h>

// GCNPre: N=100000 nodes, E=3200000 edges, F=512, H=256, C=40.
#define NN 100000
#define NE 3200000
#define NF 512
#define NH 256
#define NC 40

// CSR-build partitioning: node chunks of 32768 (64KB LDS, packed u16x2 counters).
// 256+ blocks per pass keeps all CUs busy (round-6 lesson: 64 blocks = disaster).
#define CH 32768
#define NCH 4                        // 4*32768 = 131072 >= NN
#define NPAD (NCH * CH)              // 131072
#define PARTS 64
#define SLICE ((NE + PARTS - 1) / PARTS)   // 50000
#define NBLK ((NN + 255) / 256)      // 391

typedef __attribute__((ext_vector_type(8))) short bf16x8;
typedef __attribute__((ext_vector_type(4))) float f32x4;
typedef __attribute__((ext_vector_type(4))) unsigned short u16x4;
typedef __attribute__((ext_vector_type(8))) unsigned short u16x8;

__device__ inline unsigned short f2bf(float f) {
    union { float f; unsigned u; } v; v.f = f;
    unsigned r = v.u + 0x7fffu + ((v.u >> 16) & 1u);
    return (unsigned short)(r >> 16);
}
__device__ inline float bf2f(unsigned short s) {
    union { unsigned u; float f; } v; v.u = ((unsigned)s) << 16;
    return v.f;
}

// ---------------- CSR build (no global atomics) ----------------
// Per-(chunk,slice,node) counts are Poisson(0.5): max ~10 << 255, so u8 partials are safe.

__global__ __launch_bounds__(512) void hist2_kernel(const int* __restrict__ ei,
                                                    unsigned char* __restrict__ rpart8,
                                                    unsigned char* __restrict__ cpart8) {
    __shared__ unsigned h[CH / 2];   // u16-packed counters, 64KB
    const int chunk = blockIdx.x, part = blockIdx.y, which = blockIdx.z;
    const int* src = which ? (ei + NE) : ei;
    unsigned char* outp = which ? cpart8 : rpart8;
    const int lo = chunk * CH;
    for (int i = threadIdx.x; i < CH / 2; i += 512) h[i] = 0;
    __syncthreads();
    const int e1 = min((part + 1) * SLICE, NE);
    for (int e = part * SLICE + threadIdx.x; e < e1; e += 512) {
        unsigned v = (unsigned)(src[e] - lo);
        if (v < CH) atomicAdd(&h[v >> 1], 1u << ((v & 1) << 4));
    }
    __syncthreads();
    unsigned char* dst = outp + (size_t)part * NPAD + lo;
    for (int i = threadIdx.x; i < CH; i += 512)
        dst[i] = (unsigned char)((h[i >> 1] >> ((i & 1) << 4)) & 0xffu);
}

__global__ __launch_bounds__(256) void reduce_kernel(const unsigned char* __restrict__ rpart8,
                                                     const unsigned char* __restrict__ cpart8,
                                                     int* __restrict__ row_cnt, float* __restrict__ dis,
                                                     int* __restrict__ bsum) {
    __shared__ int s[256];
    const int tid = threadIdx.x;
    const int v = blockIdx.x * 256 + tid;
    unsigned rs = 0, cs = 0;
    if (v < NN) {
        #pragma unroll 1
        for (int p = 0; p < PARTS; p++) {
            rs += rpart8[(size_t)p * NPAD + v];
            cs += cpart8[(size_t)p * NPAD + v];
        }
        row_cnt[v] = (int)rs;
        dis[v] = rsqrtf((float)cs + 1.0f);
    }
    s[tid] = (int)rs;
    __syncthreads();
    #pragma unroll
    for (int o = 128; o > 0; o >>= 1) {
        if (tid < o) s[tid] += s[tid + o];
        __syncthreads();
    }
    if (tid == 0) bsum[blockIdx.x] = s[0];
}

__global__ __launch_bounds__(512) void scanb_kernel(const int* __restrict__ bsum,
                                                    int* __restrict__ boff) {
    __shared__ int s[512];
    const int t = threadIdx.x;
    int v = (t < NBLK) ? bsum[t] : 0;
    s[t] = v;
    __syncthreads();
    #pragma unroll
    for (int o = 1; o < 512; o <<= 1) {
        int u = (t >= o) ? s[t - o] : 0;
        __syncthreads();
        s[t] += u;
        __syncthreads();
    }
    if (t < NBLK) boff[t] = s[t] - v;   // exclusive
}

__global__ __launch_bounds__(256) void rstart2_kernel(const unsigned char* __restrict__ rpart8,
                                                      const int* __restrict__ row_cnt,
                                                      const int* __restrict__ boff,
                                                      int* __restrict__ row_ptr,
                                                      unsigned* __restrict__ rbase) {
    __shared__ int s[256];
    const int tid = threadIdx.x;
    const int v = blockIdx.x * 256 + tid;
    int cnt = (v < NN) ? row_cnt[v] : 0;
    s[tid] = cnt;
    __syncthreads();
    #pragma unroll
    for (int o = 1; o < 256; o <<= 1) {
        int u = (tid >= o) ? s[tid - o] : 0;
        __syncthreads();
        s[tid] += u;
        __syncthreads();
    }
    if (v < NN) {
        unsigned run = (unsigned)(boff[blockIdx.x] + s[tid] - cnt);
        row_ptr[v] = (int)run;
        #pragma unroll 1
        for (int p = 0; p < PARTS; p++) {
            size_t i = (size_t)p * NPAD + v;
            rbase[i] = run;
            run += rpart8[i];
        }
    }
    if (v == NN) row_ptr[NN] = NE;
}

__global__ __launch_bounds__(512) void fill2d_kernel(const int* __restrict__ ei,
                                                     const unsigned* __restrict__ rbase,
                                                     const float* __restrict__ dis,
                                                     int2* __restrict__ csr) {
    __shared__ unsigned cur[CH / 2];
    const int chunk = blockIdx.x, part = blockIdx.y;
    const int lo = chunk * CH;
    for (int i = threadIdx.x; i < CH / 2; i += 512) cur[i] = 0;
    __syncthreads();
    const unsigned* base = rbase + (size_t)part * NPAD + lo;
    const int e1 = min((part + 1) * SLICE, NE);
    for (int e = part * SLICE + threadIdx.x; e < e1; e += 512) {
        int r = ei[e];
        unsigned rr = (unsigned)(r - lo);
        if (rr < CH) {
            int c = ei[NE + e];
            unsigned sh = (rr & 1) << 4;
            unsigned old = atomicAdd(&cur[rr >> 1], 1u << sh);
            unsigned p = (old >> sh) & 0xffffu;
            unsigned idx = base[rr] + p;
            int2 rec;
            rec.x = c;
            rec.y = __float_as_int(dis[r] * dis[c]);
            csr[idx] = rec;
        }
    }
}

// ---------------- weight transpose + bf16 cast (fused) ----------------
__global__ void wtrans_all(const float* __restrict__ Wm, const float* __restrict__ W1,
                           const float* __restrict__ W2, unsigned short* __restrict__ WTm,
                           unsigned short* __restrict__ W1T, unsigned short* __restrict__ W2T) {
    int t = blockIdx.x * 256 + threadIdx.x;
    if (t < NH * NF) {                   // WTm[n][k] = Wm[k][n]
        int n = t / NF, k = t % NF;
        WTm[t] = f2bf(Wm[(long)k * NH + n]);
        return;
    }
    t -= NH * NF;
    if (t < NH * NH) {                   // W1T[n][k] = W1[k][n]
        int n = t / NH, k = t % NH;
        W1T[t] = f2bf(W1[(long)k * NH + n]);
        return;
    }
    t -= NH * NH;
    if (t < 64 * NH) {                   // W2T[n][k] = W2[k][n], padded to 64 rows
        int n = t / NH, k = t % NH;
        W2T[t] = (n < NC) ? f2bf(W2[(long)k * NC + n]) : (unsigned short)0;
    }
}

// ---------------- fused GEMM1+GEMM2 ----------------
// Block: 128 rows. Stage 1: h0 = relu(x[128,512] @ WTm^T + b) -> LDS (bf16, swizzled).
// Stage 2: t1[128,256] = h0 @ W1T^T -> global. h0 never touches HBM.
__global__ __launch_bounds__(512)
void gemm12_kernel(const float* __restrict__ x, const unsigned short* __restrict__ WTm,
                   const float* __restrict__ bmlp, const unsigned short* __restrict__ W1T,
                   unsigned short* __restrict__ t1, int M) {
    __shared__ char smem[81920];
    short* h0s = (short*)smem;                 // [128][256] bf16, chunk-swizzled (64KB)
    short* As  = (short*)smem;                 // stage1 A [128][32]  (overlays h0s; dead before h0s writes)
    short* Bs  = (short*)(smem + 8192);        // stage1 B [256][32]
    short* Bs2 = (short*)(smem + 65536);       // stage2 B [256][32]  (16KB)

    const int tid = threadIdx.x;
    const int lane = tid & 63;
    const int wid = tid >> 6;          // 8 waves
    const int wr = wid >> 1;           // 0..3
    const int wc = wid & 1;            // 0..1
    const long bm = (long)blockIdx.x * 128;
    const int l15 = lane & 15, g = lane >> 4, l4 = lane >> 4;

    f32x4 acc[2][8];
    #pragma unroll
    for (int i = 0; i < 2; i++)
        #pragma unroll
        for (int j = 0; j < 8; j++) acc[i][j] = (f32x4){0.f, 0.f, 0.f, 0.f};

    // ---- stage 1: K = 512 over x (fp32) and WTm ----
    for (int k0 = 0; k0 < NF; k0 += 32) {
        {   // A tile 128x32
            int ch = tid;
            int row = ch >> 2, c = ch & 3;
            int sw = c ^ (row & 3) ^ ((row >> 2) & 3);
            long gr = bm + row;
            bf16x8 w = (bf16x8){0, 0, 0, 0, 0, 0, 0, 0};
            if (gr < M) {
                float4 v0 = *(const float4*)(x + gr * NF + k0 + c * 8);
                float4 v1 = *(const float4*)(x + gr * NF + k0 + c * 8 + 4);
                w[0] = (short)f2bf(v0.x); w[1] = (short)f2bf(v0.y);
                w[2] = (short)f2bf(v0.z); w[3] = (short)f2bf(v0.w);
                w[4] = (short)f2bf(v1.x); w[5] = (short)f2bf(v1.y);
                w[6] = (short)f2bf(v1.z); w[7] = (short)f2bf(v1.w);
            }
            *(bf16x8*)(As + row * 32 + sw * 8) = w;
        }
        #pragma unroll
        for (int i = 0; i < 2; i++) {   // B tile 256x32
            int ch = tid + i * 512;
            int row = ch >> 2, c = ch & 3;
            int sw = c ^ (row & 3) ^ ((row >> 2) & 3);
            bf16x8 w = *(const bf16x8*)(WTm + (long)row * NF + k0 + c * 8);
            *(bf16x8*)(Bs + row * 32 + sw * 8) = w;
        }
        __syncthreads();

        bf16x8 a[2];
        #pragma unroll
        for (int mi = 0; mi < 2; mi++) {
            int row = wr * 32 + mi * 16 + l15;
            int sw = g ^ (row & 3) ^ ((row >> 2) & 3);
            a[mi] = *(const bf16x8*)(As + row * 32 + sw * 8);
        }
        #pragma unroll
        for (int ni = 0; ni < 8; ni++) {
            int row = wc * 128 + ni * 16 + l15;
            int sw = g ^ (row & 3) ^ ((row >> 2) & 3);
            bf16x8 b = *(const bf16x8*)(Bs + row * 32 + sw * 8);
            #pragma unroll
            for (int mi = 0; mi < 2; mi++)
                acc[mi][ni] = __builtin_amdgcn_mfma_f32_16x16x32_bf16(a[mi], b, acc[mi][ni], 0, 0, 0);
        }
        __syncthreads();
    }

    // ---- h0 tile (relu+bias, bf16) -> LDS, chunk-swizzled: addr = row*256 + ((cc^(row&7))<<3) + (col&7)
    #pragma unroll
    for (int mi = 0; mi < 2; mi++) {
        int r0 = wr * 32 + mi * 16 + l4 * 4;
        #pragma unroll
        for (int ni = 0; ni < 8; ni++) {
            int gc = wc * 128 + ni * 16 + l15;
            float bv = bmlp[gc];
            int cc = gc >> 3, c7 = gc & 7;
            #pragma unroll
            for (int q = 0; q < 4; q++) {
                int row = r0 + q;
                float v = fmaxf(acc[mi][ni][q] + bv, 0.f);
                h0s[row * 256 + ((cc ^ (row & 7)) << 3) + c7] = (short)f2bf(v);
            }
        }
    }

    #pragma unroll
    for (int i = 0; i < 2; i++)
        #pragma unroll
        for (int j = 0; j < 8; j++) acc[i][j] = (f32x4){0.f, 0.f, 0.f, 0.f};

    // ---- stage 2: K = 256 over h0s and W1T ----
    for (int k2 = 0; k2 < NH; k2 += 32) {
        #pragma unroll
        for (int i = 0; i < 2; i++) {   // B tile 256x32 from W1T
            int ch = tid + i * 512;
            int row = ch >> 2, c = ch & 3;
            int sw = c ^ (row & 3) ^ ((row >> 2) & 3);
            bf16x8 w = *(const bf16x8*)(W1T + (long)row * NH + k2 + c * 8);
            *(bf16x8*)(Bs2 + row * 32 + sw * 8) = w;
        }
        __syncthreads();   // also orders h0s writes before first reads

        bf16x8 a[2];
        #pragma unroll
        for (int mi = 0; mi < 2; mi++) {
            int row = wr * 32 + mi * 16 + l15;
            int cc = (k2 >> 3) + g;
            a[mi] = *(const bf16x8*)(h0s + row * 256 + ((cc ^ (row & 7)) << 3));
        }
        #pragma unroll
        for (int ni = 0; ni < 8; ni++) {
            int row = wc * 128 + ni * 16 + l15;
            int sw = g ^ (row & 3) ^ ((row >> 2) & 3);
            bf16x8 b = *(const bf16x8*)(Bs2 + row * 32 + sw * 8);
            #pragma unroll
            for (int mi = 0; mi < 2; mi++)
                acc[mi][ni] = __builtin_amdgcn_mfma_f32_16x16x32_bf16(a[mi], b, acc[mi][ni], 0, 0, 0);
        }
        __syncthreads();
    }

    // ---- t1 write ----
    #pragma unroll
    for (int mi = 0; mi < 2; mi++) {
        long gr0 = bm + wr * 32 + mi * 16 + l4 * 4;
        #pragma unroll
        for (int ni = 0; ni < 8; ni++) {
            int gc = wc * 128 + ni * 16 + l15;
            #pragma unroll
            for (int q = 0; q < 4; q++) {
                long gr = gr0 + q;
                if (gr < M) t1[gr * NH + gc] = f2bf(acc[mi][ni][q]);
            }
        }
    }
}

// ---------------- GEMM3 (h1 @ W2 -> t2p, ldc=40 packed) ----------------
__global__ __launch_bounds__(256)
void gemm3_kernel(const unsigned short* __restrict__ A, const unsigned short* __restrict__ W2T,
                  unsigned short* __restrict__ C, int M) {
    constexpr int BM = 128, BN = 64, BK = 32;
    __shared__ short As[BM * BK];
    __shared__ short Bs[BN * BK];

    const int tid = threadIdx.x;
    const int lane = tid & 63;
    const int wid = tid >> 6;      // 4 waves, 1 column
    const int wr = wid;
    const long bm = (long)blockIdx.x * BM;
    const int l15 = lane & 15, g = lane >> 4, l4 = lane >> 4;

    f32x4 acc[2][4];
    #pragma unroll
    for (int i = 0; i < 2; i++)
        #pragma unroll
        for (int j = 0; j < 4; j++) acc[i][j] = (f32x4){0.f, 0.f, 0.f, 0.f};

    for (int k0 = 0; k0 < NH; k0 += BK) {
        #pragma unroll
        for (int i = 0; i < 2; i++) {
            int ch = tid + i * 256;
            int row = ch >> 2, c = ch & 3;
            int sw = c ^ (row & 3) ^ ((row >> 2) & 3);
            long gr = bm + row;
            bf16x8 w = (bf16x8){0, 0, 0, 0, 0, 0, 0, 0};
            if (gr < M) w = *(const bf16x8*)(A + gr * NH + k0 + c * 8);
            *(bf16x8*)(As + row * BK + sw * 8) = w;
        }
        {
            int ch = tid;
            int row = ch >> 2, c = ch & 3;
            int sw = c ^ (row & 3) ^ ((row >> 2) & 3);
            bf16x8 w = *(const bf16x8*)(W2T + (long)row * NH + k0 + c * 8);
            *(bf16x8*)(Bs + row * BK + sw * 8) = w;
        }
        __syncthreads();

        bf16x8 a[2];
        #pragma unroll
        for (int mi = 0; mi < 2; mi++) {
            int row = wr * 32 + mi * 16 + l15;
            int sw = g ^ (row & 3) ^ ((row >> 2) & 3);
            a[mi] = *(const bf16x8*)(As + row * BK + sw * 8);
        }
        #pragma unroll
        for (int ni = 0; ni < 4; ni++) {
            int row = ni * 16 + l15;
            int sw = g ^ (row & 3) ^ ((row >> 2) & 3);
            bf16x8 b = *(const bf16x8*)(Bs + row * BK + sw * 8);
            #pragma unroll
            for (int mi = 0; mi < 2; mi++)
                acc[mi][ni] = __builtin_amdgcn_mfma_f32_16x16x32_bf16(a[mi], b, acc[mi][ni], 0, 0, 0);
        }
        __syncthreads();
    }

    #pragma unroll
    for (int mi = 0; mi < 2; mi++) {
        long gr0 = bm + wr * 32 + mi * 16 + l4 * 4;
        #pragma unroll
        for (int ni = 0; ni < 4; ni++) {
            int gc = ni * 16 + l15;
            if (gc >= NC) continue;
            #pragma unroll
            for (int q = 0; q < 4; q++) {
                long gr = gr0 + q;
                if (gr < M) C[gr * NC + gc] = f2bf(acc[mi][ni][q]);
            }
        }
    }
}

// ---------------- aggregation (gather SpMM, bf16 payload) ----------------
__global__ void agg256_kernel(const unsigned short* __restrict__ t, const int* __restrict__ row_ptr,
                              const int2* __restrict__ csr, const float* __restrict__ dis,
                              const float* __restrict__ bias, unsigned short* __restrict__ out, int n) {
    const int wid = threadIdx.x >> 6, lane = threadIdx.x & 63;
    const int node = blockIdx.x * 4 + wid;
    if (node >= n) return;
    const int half = lane >> 5;
    const int f0 = (lane & 31) * 8;
    const float d = dis[node];
    float a[8];
    if (half == 0) {
        u16x8 sv = *(const u16x8*)(t + (long)node * NH + f0);
        float d2 = d * d;
        #pragma unroll
        for (int j = 0; j < 8; j++) a[j] = bf2f(sv[j]) * d2;
    } else {
        #pragma unroll
        for (int j = 0; j < 8; j++) a[j] = 0.f;
    }
    const int lo = row_ptr[node], hi = row_ptr[node + 1];
    int ee = lo + half;
    for (; ee + 6 < hi; ee += 8) {
        int2 r0 = csr[ee];
        int2 r1 = csr[ee + 2];
        int2 r2 = csr[ee + 4];
        int2 r3 = csr[ee + 6];
        u16x8 v0 = *(const u16x8*)(t + (long)r0.x * NH + f0);
        u16x8 v1 = *(const u16x8*)(t + (long)r1.x * NH + f0);
        u16x8 v2 = *(const u16x8*)(t + (long)r2.x * NH + f0);
        u16x8 v3 = *(const u16x8*)(t + (long)r3.x * NH + f0);
        float w0 = __int_as_float(r0.y), w1 = __int_as_float(r1.y);
        float w2 = __int_as_float(r2.y), w3 = __int_as_float(r3.y);
        #pragma unroll
        for (int j = 0; j < 8; j++)
            a[j] += (bf2f(v0[j]) * w0 + bf2f(v1[j]) * w1) + (bf2f(v2[j]) * w2 + bf2f(v3[j]) * w3);
    }
    for (; ee + 2 < hi; ee += 4) {
        int2 r0 = csr[ee];
        int2 r1 = csr[ee + 2];
        u16x8 v0 = *(const u16x8*)(t + (long)r0.x * NH + f0);
        u16x8 v1 = *(const u16x8*)(t + (long)r1.x * NH + f0);
        float w0 = __int_as_float(r0.y), w1 = __int_as_float(r1.y);
        #pragma unroll
        for (int j = 0; j < 8; j++)
            a[j] += bf2f(v0[j]) * w0 + bf2f(v1[j]) * w1;
    }
    if (ee < hi) {
        int2 r0 = csr[ee];
        u16x8 v0 = *(const u16x8*)(t + (long)r0.x * NH + f0);
        float w0 = __int_as_float(r0.y);
        #pragma unroll
        for (int j = 0; j < 8; j++) a[j] += bf2f(v0[j]) * w0;
    }
    #pragma unroll
    for (int j = 0; j < 8; j++) a[j] += __shfl_xor(a[j], 32);
    if (half == 0) {
        u16x8 o;
        #pragma unroll
        for (int j = 0; j < 8; j++)
            o[j] = f2bf(fmaxf(a[j] + bias[f0 + j], 0.f));
        *(u16x8*)(out + (long)node * NH + f0) = o;
    }
}

// agg40: t2p rows are 40 bf16 (80B, 16B-aligned). 8 groups of 8 lanes; 5 lanes/group active.
__global__ void agg40_kernel(const unsigned short* __restrict__ t, const int* __restrict__ row_ptr,
                             const int2* __restrict__ csr, const float* __restrict__ dis,
                             const float* __restrict__ bias, float* __restrict__ out, int n) {
    const int wid = threadIdx.x >> 6, lane = threadIdx.x & 63;
    const int node = blockIdx.x * 4 + wid;
    if (node >= n) return;
    const int g = lane >> 3;
    const int f0 = (lane & 7) * 8;
    const bool act = f0 < NC;
    const float d = dis[node];
    float a[8];
    #pragma unroll
    for (int j = 0; j < 8; j++) a[j] = 0.f;
    const int lo = row_ptr[node], hi = row_ptr[node + 1];
    if (act) {
        if (g == 0) {
            u16x8 sv = *(const u16x8*)(t + (long)node * NC + f0);
            float d2 = d * d;
            #pragma unroll
            for (int j = 0; j < 8; j++) a[j] = bf2f(sv[j]) * d2;
        }
        int ee = lo + g;
        for (; ee + 8 < hi; ee += 16) {
            int2 r0 = csr[ee];
            int2 r1 = csr[ee + 8];
            u16x8 v0 = *(const u16x8*)(t + (long)r0.x * NC + f0);
            u16x8 v1 = *(const u16x8*)(t + (long)r1.x * NC + f0);
            float w0 = __int_as_float(r0.y), w1 = __int_as_float(r1.y);
            #pragma unroll
            for (int j = 0; j < 8; j++)
                a[j] += bf2f(v0[j]) * w0 + bf2f(v1[j]) * w1;
        }
        if (ee < hi) {
            int2 r0 = csr[ee];
            u16x8 v0 = *(const u16x8*)(t + (long)r0.x * NC + f0);
            float w0 = __int_as_float(r0.y);
            #pragma unroll
            for (int j = 0; j < 8; j++) a[j] += bf2f(v0[j]) * w0;
        }
    }
    #pragma unroll
    for (int s = 8; s < 64; s <<= 1)
        #pragma unroll
        for (int j = 0; j < 8; j++) a[j] += __shfl_xor(a[j], s);
    if (g == 0 && act) {
        float4 o0, o1;
        o0.x = a[0] + bias[f0 + 0]; o0.y = a[1] + bias[f0 + 1];
        o0.z = a[2] + bias[f0 + 2]; o0.w = a[3] + bias[f0 + 3];
        o1.x = a[4] + bias[f0 + 4]; o1.y = a[5] + bias[f0 + 5];
        o1.z = a[6] + bias[f0 + 6]; o1.w = a[7] + bias[f0 + 7];
        float* dst = out + (long)node * NC + f0;
        *(float4*)dst = o0;
        *(float4*)(dst + 4) = o1;
    }
}

// ---------------- launch ----------------

extern "C" void kernel_launch(void* const* d_in, const int* in_sizes, int n_in,
                              void* d_out, int out_size, void* d_ws, size_t ws_size,
                              hipStream_t stream) {
    const float* x     = (const float*)d_in[0];
    const int*   ei    = (const int*)d_in[1];
    const float* W_mlp = (const float*)d_in[2];
    const float* b_mlp = (const float*)d_in[3];
    const float* W1    = (const float*)d_in[4];
    const float* b1    = (const float*)d_in[5];
    const float* W2    = (const float*)d_in[6];
    const float* b2    = (const float*)d_in[7];
    float* out = (float*)d_out;

    // workspace layout (float units)
    float* ws = (float*)d_ws;
    size_t off = 0;
    float*    dis     = ws + off; off += 100096;
    int*      row_cnt = (int*)(ws + off); off += 100096;
    int*      row_ptr = (int*)(ws + off); off += 100096;
    int*      bsum    = (int*)(ws + off); off += 512;
    int*      boff    = (int*)(ws + off); off += 512;
    unsigned char* rpart8 = (unsigned char*)(ws + off); off += (size_t)PARTS * NPAD / 4;
    unsigned char* cpart8 = (unsigned char*)(ws + off); off += (size_t)PARTS * NPAD / 4;
    unsigned* rbase   = (unsigned*)(ws + off); off += (size_t)PARTS * NPAD;
    int2*     csr     = (int2*)(ws + off); off += (size_t)NE * 2;
    unsigned short* WTm = (unsigned short*)(ws + off); off += (NH * NF) / 2;
    unsigned short* W1T = (unsigned short*)(ws + off); off += (NH * NH) / 2;
    unsigned short* W2T = (unsigned short*)(ws + off); off += (64 * NH) / 2;
    unsigned short* t1  = (unsigned short*)(ws + off); off += (size_t)NN * NH / 2;
    unsigned short* h1  = (unsigned short*)(ws + off); off += (size_t)NN * NH / 2;
    unsigned short* t2p = (unsigned short*)(ws + off); off += ((size_t)NN * NC + 8) / 2;
    (void)ws_size;

    dim3 gh(NCH, PARTS, 2);
    hist2_kernel<<<gh, 512, 0, stream>>>(ei, rpart8, cpart8);
    reduce_kernel<<<NBLK, 256, 0, stream>>>(rpart8, cpart8, row_cnt, dis, bsum);
    scanb_kernel<<<1, 512, 0, stream>>>(bsum, boff);
    rstart2_kernel<<<NBLK, 256, 0, stream>>>(rpart8, row_cnt, boff, row_ptr, rbase);
    dim3 gf(NCH, PARTS);
    fill2d_kernel<<<gf, 512, 0, stream>>>(ei, rbase, dis, csr);

    wtrans_all<<<(NH * NF + NH * NH + 64 * NH + 255) / 256, 256, 0, stream>>>(
        W_mlp, W1, W2, WTm, W1T, W2T);

    const int mb = (NN + 127) / 128;  // 782
    // t1 = (relu(x@Wm+b)) @ W1, fused (h0 stays in LDS)
    gemm12_kernel<<<mb, 512, 0, stream>>>(x, WTm, b_mlp, W1T, t1, NN);
    // h1 = relu(agg(t1) + b1)
    agg256_kernel<<<(NN + 3) / 4, 256, 0, stream>>>(t1, row_ptr, csr, dis, b1, h1, NN);
    // t2p = h1 @ W2 (40-wide rows)
    gemm3_kernel<<<mb, 256, 0, stream>>>(h1, W2T, t2p, NN);
    // out = agg(t2p) + b2
    agg40_kernel<<<(NN + 3) / 4, 256, 0, stream>>>(t2p, row_ptr, csr, dis, b2, out, NN);
}